// Round 10
// baseline (344.546 us; speedup 1.0000x reference)
//
#include <hip/hip_runtime.h>
#include <cstdint>
#include <cstddef>

#define DEVI __device__ __forceinline__

typedef __attribute__((ext_vector_type(8))) short short8;
typedef __attribute__((ext_vector_type(4))) float f32x4;
typedef __attribute__((ext_vector_type(2))) unsigned short u16x2;
typedef __attribute__((ext_vector_type(4))) unsigned short u16x4;
typedef __attribute__((ext_vector_type(8))) unsigned short u16x8;

#define Bn 8
#define Cn 512
#define HWn 4096
#define Mtot 32768

DEVI float b2f(unsigned short u) {
  union { uint32_t u; float f; } c; c.u = ((uint32_t)u) << 16; return c.f;
}
DEVI unsigned short f2b(float f) {
  union { float f; uint32_t u; } c; c.f = f;
  uint32_t u = c.u + 0x7fffu + ((c.u >> 16) & 1u);
  return (unsigned short)(u >> 16);
}
// tanh-form gelu; |err| vs exact erf-gelu ~1e-3, well under bf16 output noise
DEVI float gelu_fast(float x) {
  float y = 0.7978845608f * (x + 0.044715f * x * x * x);
  float e = __expf(2.0f * y);
  float t = 1.0f - 2.0f / (e + 1.0f);
  return 0.5f * x * (1.0f + t);
}

DEVI void async16(const void* g, void* l) {
  __builtin_amdgcn_global_load_lds((const __attribute__((address_space(1))) uint32_t*)g,
                                   (__attribute__((address_space(3))) uint32_t*)l, 16, 0, 0);
}

// stage `passes`*64 rows x 64 k of bf16 into LDS (512-thread kernels).
// linear LDS dest (wave-uniform base + lane*16), XOR-pre-swizzled global source.
DEVI void stageN(const unsigned short* __restrict__ src, int ld, int row0, int kt,
                 char* lds, int t, int passes) {
  const int w = t >> 6;
  const int srow = t >> 3, sph = t & 7;
  for (int i = 0; i < passes; ++i) {
    int row = i * 64 + srow;
    int slog = sph ^ (row & 7);
    async16(src + (size_t)(row0 + row) * ld + kt + slog * 8, lds + i * 8192 + w * 1024);
  }
}

// stage 128 rows x 64 k (256-thread kernels: k_z, k_attn_part helpers)
DEVI void stage128(const unsigned short* __restrict__ src, int ld, int row0, int kt,
                   char* lds, int t) {
  const int w = t >> 6;
  const int srow = t >> 3, sph = t & 7;
#pragma unroll
  for (int i = 0; i < 4; ++i) {
    int row = i * 32 + srow;
    int slog = sph ^ (row & 7);
    async16(src + (size_t)(row0 + row) * ld + kt + slog * 8, lds + i * 4096 + w * 1024);
  }
}

// one K=64 compute step (2 x k32, 32 MFMA per wave); As/Bs row stride 64, slot-XOR swizzle.
// wr selects 64-row A block, wc selects 64-row B block (wc may range 0..3 for wide B).
DEVI void gemm_compute(const unsigned short* As, const unsigned short* Bs,
                       int wr, int wc, int l15, int l4, f32x4 (&acc)[4][4]) {
#pragma unroll
  for (int ks = 0; ks < 2; ++ks) {
    short8 af[4], bfv[4];
#pragma unroll
    for (int m = 0; m < 4; ++m) {
      int row = wr * 64 + m * 16 + l15;
      int slog = ks * 4 + l4;
      af[m] = *(const short8*)&As[row * 64 + ((slog ^ (row & 7)) << 3)];
    }
#pragma unroll
    for (int n = 0; n < 4; ++n) {
      int row = wc * 64 + n * 16 + l15;
      int slog = ks * 4 + l4;
      bfv[n] = *(const short8*)&Bs[row * 64 + ((slog ^ (row & 7)) << 3)];
    }
#pragma unroll
    for (int m = 0; m < 4; ++m)
#pragma unroll
      for (int n = 0; n < 4; ++n)
        acc[m][n] = __builtin_amdgcn_mfma_f32_16x16x32_bf16(af[m], bfv[n], acc[m][n], 0, 0, 0);
  }
}

// Wide NT GEMM: 128m x 256n tile, 512 threads (8 waves = 2M x 4N), shared A-tile.
// Per K-step: stage A(2 passes)+B(4 passes) = 6 loads/thread, 64 MFMA/SIMD (2x the
// 128x128 version per barrier-pair). LDS 48KB -> 2 blocks/CU (VGPR cap 128).
// XCD-chunked swizzle: each XCD owns 32 contiguous m-tiles, n fastest within.
// MODE 0: QKV (bias/output routing by column region, col sq-norm for Q,K).
// MODE 1: gelu(acc+bias). MODE 2: acc+bias+res.
template <int MODE>
__global__ __launch_bounds__(512, 4) void k_gw(
    const unsigned short* __restrict__ A, const unsigned short* __restrict__ A2,
    const unsigned short* __restrict__ W,
    const float* __restrict__ bias, const float* __restrict__ bias2,
    const float* __restrict__ bias3, const unsigned short* __restrict__ res,
    unsigned short* __restrict__ out, unsigned short* __restrict__ out2,
    int K, int N, float* __restrict__ sqQ, float* __restrict__ sqK) {
  __shared__ __align__(16) char smem[49152];
  unsigned short* As = (unsigned short*)smem;            // 128 x 64
  unsigned short* Bs = (unsigned short*)(smem + 16384);  // 256 x 64
  const int NT2 = gridDim.x;
  const int lin = blockIdx.x + NT2 * blockIdx.y;
  const int xcd = lin & 7, j = lin >> 3;
  const int mt = xcd * 32 + j / NT2;
  const int nt2 = j % NT2;
  const int m0 = mt * 128, n0 = nt2 * 256;
  const unsigned short* Ag = (MODE == 0 && nt2 >= 2) ? A2 : A;
  const int t = threadIdx.x, w = t >> 6, lane = t & 63;
  const int wr = w >> 2, wc = w & 3, l15 = lane & 15, l4 = lane >> 4;
  f32x4 acc[4][4] = {};

  for (int kt = 0; kt < K; kt += 64) {
    stageN(Ag, K, m0, kt, (char*)As, t, 2);
    stageN(W, K, n0, kt, (char*)Bs, t, 4);
    __syncthreads();
    gemm_compute(As, Bs, wr, wc, l15, l4, acc);
    __syncthreads();
  }

  unsigned short* Cs = (unsigned short*)smem;  // [128][132] stash, two 128-col halves
#pragma unroll
  for (int hh = 0; hh < 2; ++hh) {
    __syncthreads();
    if ((wc >> 1) == hh) {
#pragma unroll
      for (int n = 0; n < 4; ++n) {
        int cnl = (wc & 1) * 64 + n * 16 + l15;       // 0..127 within half
        int colg = n0 + hh * 128 + cnl;               // global output column
        float bn;
        if (MODE == 0)
          bn = (colg < 512) ? bias[colg] : (colg < 1024 ? bias2[colg - 512] : bias3[colg - 1024]);
        else
          bn = bias[colg];
        float s2 = 0.f;
#pragma unroll
        for (int m = 0; m < 4; ++m) {
          int rb = wr * 64 + m * 16 + l4 * 4;
#pragma unroll
          for (int q = 0; q < 4; ++q) {
            float v = acc[m][n][q] + bn;
            if (MODE == 1) v = gelu_fast(v);
            if (MODE == 0) s2 += v * v;
            Cs[(rb + q) * 132 + cnl] = f2b(v);
          }
        }
        if (MODE == 0 && colg < 1024) {
          float* sq = (colg < 512) ? sqQ : sqK;
          s2 += __shfl_xor(s2, 16, 64);
          s2 += __shfl_xor(s2, 32, 64);
          if (l4 == 0) atomicAdd(&sq[(m0 >> 12) * Cn + (colg & 511)], s2);
        }
      }
    }
    __syncthreads();
    int r = t >> 2, c = (t & 3) * 32;
    int colg0 = n0 + hh * 128 + c;
    unsigned short* ob;
    size_t base;
    if (MODE == 0) {
      if (colg0 < 512) { ob = out; base = (size_t)(m0 + r) * 512 + colg0; }
      else { ob = out2; base = (size_t)(m0 + r) * 1024 + (colg0 - 512); }
    } else {
      ob = out;
      base = (size_t)(m0 + r) * N + colg0;
    }
#pragma unroll
    for (int u = 0; u < 4; ++u) {
      u16x8 v = *(const u16x8*)&Cs[r * 132 + c + u * 8];
      if (MODE == 2) {
        u16x8 rv = *(const u16x8*)&res[base + u * 8];
#pragma unroll
        for (int jj = 0; jj < 8; ++jj) v[jj] = f2b(b2f(v[jj]) + b2f(rv[jj]));
      }
      *(u16x8*)&ob[base + u * 8] = v;
    }
  }
}

// one K=64 compute step for the 256x256 tile: 8 waves (2M x 4N), per-wave 128x64 out.
DEVI void compute256(const unsigned short* Ab, const unsigned short* Bb,
                     int wr, int wc, int l15, int l4, f32x4 (&acc)[8][4]) {
#pragma unroll
  for (int ks = 0; ks < 2; ++ks) {
    short8 aF[8], bF[4];
#pragma unroll
    for (int mf = 0; mf < 8; ++mf) {
      int row = wr * 128 + mf * 16 + l15;
      aF[mf] = *(const short8*)&Ab[row * 64 + (((ks * 4 + l4) ^ (row & 7)) << 3)];
    }
#pragma unroll
    for (int nf = 0; nf < 4; ++nf) {
      int row = wc * 64 + nf * 16 + l15;
      bF[nf] = *(const short8*)&Bb[row * 64 + (((ks * 4 + l4) ^ (row & 7)) << 3)];
    }
#pragma unroll
    for (int mf = 0; mf < 8; ++mf)
#pragma unroll
      for (int nf = 0; nf < 4; ++nf)
        acc[mf][nf] = __builtin_amdgcn_mfma_f32_16x16x32_bf16(aF[mf], bF[nf], acc[mf][nf], 0, 0, 0);
  }
}

// Final: out[b,c,n] = wo@U + bo + xo. 256x256 tile, 2-phase dbuf, coalesced fp32 epilogue.
__global__ __launch_bounds__(512, 2) void k_gemm_out(
    const unsigned short* __restrict__ Wo, const unsigned short* __restrict__ U,
    const float* __restrict__ bo, const float* __restrict__ xopt,
    const float* __restrict__ meanG, const float* __restrict__ rstdG,
    const float* __restrict__ lnw, const float* __restrict__ lnb,
    float* __restrict__ out) {
  __shared__ __align__(16) char smem[131072];
  const int lin = blockIdx.x;
  const int xcd = lin & 7, j = lin >> 3;
  const int b = xcd, mt = j & 1, nt = j >> 1;
  const int m0 = mt * 256, n0 = nt * 256;
  const unsigned short* Ub = U + (size_t)b * HWn * Cn;
  const int t = threadIdx.x, lane = t & 63;
  const int w = t >> 6, wr = w >> 2, wc = w & 3;
  const int l15 = lane & 15, l4 = lane >> 4;
  f32x4 acc[8][4] = {};

  stageN(Wo, 512, m0, 0, smem, t, 4);
  stageN(Ub, 512, n0, 0, smem + 32768, t, 4);
  __syncthreads();
  for (int kt = 0; kt < 8; ++kt) {
    if (kt + 1 < 8) {
      char* nb = smem + ((kt + 1) & 1) * 65536;
      stageN(Wo, 512, m0, (kt + 1) * 64, nb, t, 4);
      stageN(Ub, 512, n0, (kt + 1) * 64, nb + 32768, t, 4);
    }
    const unsigned short* Ab = (const unsigned short*)(smem + (kt & 1) * 65536);
    const unsigned short* Bb = (const unsigned short*)(smem + (kt & 1) * 65536 + 32768);
    compute256(Ab, Bb, wr, wc, l15, l4, acc);
    __syncthreads();
  }

  float* Fs = (float*)smem;  // [64][260] f32 stash, four c-quarters
#pragma unroll
  for (int qd = 0; qd < 4; ++qd) {
    __syncthreads();
    if (wr == (qd >> 1)) {
#pragma unroll
      for (int nf = 0; nf < 4; ++nf) {
        int cn = wc * 64 + nf * 16 + l15;
#pragma unroll
        for (int mf2 = 0; mf2 < 4; ++mf2) {
          int mf = (qd & 1) * 4 + mf2;
#pragma unroll
          for (int q = 0; q < 4; ++q)
            Fs[(mf2 * 16 + l4 * 4 + q) * 260 + cn] = acc[mf][nf][q];
        }
      }
    }
    __syncthreads();
#pragma unroll
    for (int p = 0; p < 8; ++p) {
      int cl = p * 8 + w;            // wave-uniform channel row within quarter
      int px = lane * 4;             // 4 contiguous pixels per lane -> 1KB/wave
      int c = m0 + qd * 64 + cl;
      size_t gbase = (size_t)(b * Cn + c) * HWn + n0 + px;
      f32x4 z = *(const f32x4*)&Fs[cl * 260 + px];
      f32x4 xv = *(const f32x4*)&xopt[gbase];
      f32x4 mn4 = *(const f32x4*)&meanG[b * HWn + n0 + px];
      f32x4 rs4 = *(const f32x4*)&rstdG[b * HWn + n0 + px];
      float lw = lnw[c], lb = lnb[c], bc = bo[c];
      f32x4 o;
#pragma unroll
      for (int jj = 0; jj < 4; ++jj)
        o[jj] = z[jj] + bc + (xv[jj] - mn4[jj]) * rs4[jj] * lw + lb;
      *(f32x4*)&out[gbase] = o;
    }
  }
}

// Z = V_head @ P  (M=128 pixels, N=64, K=64), epilogue adds z_opt (= XO, same layout)
__global__ __launch_bounds__(256, 2) void k_z(
    const unsigned short* __restrict__ V, int ldv, const unsigned short* __restrict__ PT,
    const unsigned short* __restrict__ XO, unsigned short* __restrict__ ZS) {
  __shared__ __align__(16) char smem[24576];
  unsigned short* As = (unsigned short*)smem;
  unsigned short* Bs = (unsigned short*)(smem + 16384);
  const int mt = blockIdx.x, bh = blockIdx.y, b = bh >> 3, h = bh & 7;
  const int t = threadIdx.x, w = t >> 6, lane = t & 63;
  const int wr = w >> 1, wc = w & 1, l15 = lane & 15, l4 = lane >> 4;
  const int srow = t >> 3, sph = t & 7;
#pragma unroll
  for (int i = 0; i < 4; ++i) {
    int row = i * 32 + srow;
    int slog = sph ^ (row & 7);
    async16(V + (size_t)(b * HWn + mt * 128 + row) * ldv + h * 64 + slog * 8,
            (char*)As + i * 4096 + w * 1024);
  }
#pragma unroll
  for (int i = 0; i < 2; ++i) {
    int row = i * 32 + srow;
    int slog = sph ^ (row & 7);
    async16(PT + (size_t)bh * 4096 + row * 64 + slog * 8, (char*)Bs + i * 4096 + w * 1024);
  }
  __syncthreads();
  f32x4 acc[4][2] = {};
#pragma unroll
  for (int ks = 0; ks < 2; ++ks) {
    short8 af[4], bfv[2];
#pragma unroll
    for (int m = 0; m < 4; ++m) {
      int row = wr * 64 + m * 16 + l15;
      int slog = ks * 4 + l4;
      af[m] = *(const short8*)&As[row * 64 + ((slog ^ (row & 7)) << 3)];
    }
#pragma unroll
    for (int n = 0; n < 2; ++n) {
      int row = wc * 32 + n * 16 + l15;
      int slog = ks * 4 + l4;
      bfv[n] = *(const short8*)&Bs[row * 64 + ((slog ^ (row & 7)) << 3)];
    }
#pragma unroll
    for (int m = 0; m < 4; ++m)
#pragma unroll
      for (int n = 0; n < 2; ++n)
        acc[m][n] = __builtin_amdgcn_mfma_f32_16x16x32_bf16(af[m], bfv[n], acc[m][n], 0, 0, 0);
  }
  __syncthreads();
  unsigned short* Cs = (unsigned short*)smem;  // [128][72]
#pragma unroll
  for (int n = 0; n < 2; ++n) {
    int e = wc * 32 + n * 16 + l15;
#pragma unroll
    for (int m = 0; m < 4; ++m) {
      int rb = wr * 64 + m * 16 + l4 * 4;
#pragma unroll
      for (int q = 0; q < 4; ++q) Cs[(rb + q) * 72 + e] = f2b(acc[m][n][q]);
    }
  }
  __syncthreads();
#pragma unroll
  for (int pass = 0; pass < 4; ++pass) {
    int r = pass * 32 + (t >> 3);
    int c = (t & 7) * 8;
    u16x8 v = *(const u16x8*)&Cs[r * 72 + c];
    size_t idx = (size_t)(b * HWn + mt * 128 + r) * Cn + h * 64 + c;
    u16x8 xo = *(const u16x8*)&XO[idx];
#pragma unroll
    for (int jj = 0; jj < 8; ++jj) v[jj] = f2b(b2f(v[jj]) + b2f(xo[jj]));
    *(u16x8*)&ZS[idx] = v;
  }
}

// LayerNorm over C per pixel; writes transposed bf16 [pixel, C]. z=0: x_opt(+stats); z=1: x_sar.
__global__ __launch_bounds__(256, 2) void k_ln(
    const float* __restrict__ x_opt, const float* __restrict__ x_sar,
    const float* __restrict__ lwo, const float* __restrict__ lbo,
    const float* __restrict__ lws, const float* __restrict__ lbs,
    unsigned short* __restrict__ XO, unsigned short* __restrict__ XS,
    float* __restrict__ meanG, float* __restrict__ rstdG) {
  const int zz = blockIdx.z;
  const float* x = zz ? x_sar : x_opt;
  const float* lw = zz ? lws : lwo;
  const float* lb = zz ? lbs : lbo;
  unsigned short* out = zz ? XS : XO;
  __shared__ unsigned short stash[512 * 34];
  __shared__ float redS[256 * 4], redQ[256 * 4];
  __shared__ float meanS[32], rstdS[32], wS[512], bS[512];
  const int b = blockIdx.y, n0 = blockIdx.x * 32;
  const int t = threadIdx.x;
  wS[t] = lw[t]; wS[t + 256] = lw[t + 256];
  bS[t] = lb[t]; bS[t + 256] = lb[t + 256];
  const int cg = t >> 3, pq = t & 7;
  float sum[4] = {}, sq[4] = {};
  for (int r = 0; r < 16; ++r) {
    int c = r * 32 + cg;
    f32x4 v = *(const f32x4*)(x + (size_t)(b * Cn + c) * HWn + n0 + pq * 4);
#pragma unroll
    for (int j = 0; j < 4; ++j) { sum[j] += v[j]; sq[j] += v[j] * v[j]; }
    u16x2 h0 = {f2b(v[0]), f2b(v[1])};
    u16x2 h1 = {f2b(v[2]), f2b(v[3])};
    *(u16x2*)&stash[c * 34 + pq * 4] = h0;
    *(u16x2*)&stash[c * 34 + pq * 4 + 2] = h1;
  }
#pragma unroll
  for (int j = 0; j < 4; ++j) { redS[t * 4 + j] = sum[j]; redQ[t * 4 + j] = sq[j]; }
  __syncthreads();
  if (t < 32) {
    float s = 0.f, qq = 0.f;
    int pqq = t >> 2, j = t & 3;
    for (int g = 0; g < 32; ++g) {
      s += redS[(g * 8 + pqq) * 4 + j];
      qq += redQ[(g * 8 + pqq) * 4 + j];
    }
    float mean = s * (1.0f / 512.0f);
    float var = qq * (1.0f / 512.0f) - mean * mean;
    float rstd = rsqrtf(var + 1e-5f);
    meanS[t] = mean; rstdS[t] = rstd;
    if (!zz) { meanG[b * HWn + n0 + t] = mean; rstdG[b * HWn + n0 + t] = rstd; }
  }
  __syncthreads();
  const int p = t >> 3, cs = t & 7;
  float mn = meanS[p], rs = rstdS[p];
  for (int ch = 0; ch < 4; ++ch) {
    u16x8 o0, o1;
#pragma unroll
    for (int j = 0; j < 16; ++j) {
      int c = ch * 128 + cs * 16 + j;
      float xv = b2f(stash[c * 34 + p]);
      unsigned short r2 = f2b((xv - mn) * rs * wS[c] + bS[c]);
      if (j < 8) o0[j] = r2; else o1[j - 8] = r2;
    }
    size_t base = (size_t)(b * HWn + n0 + p) * Cn + ch * 128 + cs * 16;
    *(u16x8*)&out[base] = o0;
    *(u16x8*)&out[base + 8] = o1;
  }
}

// MFMA partial Gram over a 512-row slice: Praw[bh][d][e] += sum_n Q[n,d]*K[n,e].
__global__ __launch_bounds__(256, 2) void k_attn_part(
    const unsigned short* __restrict__ Q, int ldq,
    const unsigned short* __restrict__ Kb, int ldk,
    float* __restrict__ Praw) {
  __shared__ __align__(16) unsigned short QT[64 * 136];
  __shared__ __align__(16) unsigned short KT[64 * 136];
  const int bh = blockIdx.x, ns = blockIdx.y, b = bh >> 3, h = bh & 7;
  const int t = threadIdx.x, w = t >> 6, lane = t & 63;
  const int l15 = lane & 15, l4 = lane >> 4;
  const int dh = w >> 1, eh = w & 1;
  const int c8 = t >> 5, rr = t & 31;
  f32x4 acc[2][2] = {};
  for (int chunk = 0; chunk < 4; ++chunk) {
    int n0 = ns * 512 + chunk * 128;
    __syncthreads();
#pragma unroll
    for (int pass = 0; pass < 2; ++pass) {
      int row = n0 + pass * 64 + 2 * rr;
      u16x8 q0 = *(const u16x8*)(Q + (size_t)(b * HWn + row) * ldq + h * 64 + c8 * 8);
      u16x8 q1 = *(const u16x8*)(Q + (size_t)(b * HWn + row + 1) * ldq + h * 64 + c8 * 8);
      u16x8 k0 = *(const u16x8*)(Kb + (size_t)(b * HWn + row) * ldk + h * 64 + c8 * 8);
      u16x8 k1 = *(const u16x8*)(Kb + (size_t)(b * HWn + row + 1) * ldk + h * 64 + c8 * 8);
#pragma unroll
      for (int j = 0; j < 8; ++j) {
        u16x2 pq = {q0[j], q1[j]};
        u16x2 pk = {k0[j], k1[j]};
        *(u16x2*)&QT[(c8 * 8 + j) * 136 + pass * 64 + 2 * rr] = pq;
        *(u16x2*)&KT[(c8 * 8 + j) * 136 + pass * 64 + 2 * rr] = pk;
      }
    }
    __syncthreads();
#pragma unroll
    for (int ks = 0; ks < 4; ++ks) {
      short8 af[2], bfv[2];
#pragma unroll
      for (int m = 0; m < 2; ++m)
        af[m] = *(const short8*)&QT[(dh * 32 + m * 16 + l15) * 136 + ks * 32 + l4 * 8];
#pragma unroll
      for (int n = 0; n < 2; ++n)
        bfv[n] = *(const short8*)&KT[(eh * 32 + n * 16 + l15) * 136 + ks * 32 + l4 * 8];
#pragma unroll
      for (int m = 0; m < 2; ++m)
#pragma unroll
        for (int n = 0; n < 2; ++n)
          acc[m][n] = __builtin_amdgcn_mfma_f32_16x16x32_bf16(af[m], bfv[n], acc[m][n], 0, 0, 0);
    }
  }
#pragma unroll
  for (int m = 0; m < 2; ++m)
#pragma unroll
    for (int n = 0; n < 2; ++n)
#pragma unroll
      for (int q = 0; q < 4; ++q) {
        int dd = dh * 32 + m * 16 + l4 * 4 + q;
        int ee = eh * 32 + n * 16 + l15;
        atomicAdd(&Praw[(size_t)bh * 4096 + dd * 64 + ee], acc[m][n][q]);
      }
}

// scale by rq*rk/8, row softmax, store PT[bh][e][d] bf16 (layout k_z consumes)
__global__ __launch_bounds__(256, 2) void k_softmax(
    const float* __restrict__ Praw, const float* __restrict__ sqQ,
    const float* __restrict__ sqK, unsigned short* __restrict__ PT) {
  __shared__ float P3[64 * 66];
  const int bh = blockIdx.x, b = bh >> 3, h = bh & 7;
  const int t = threadIdx.x, w = t >> 6, lane = t & 63;
  float rk = 1.0f / fmaxf(sqrtf(sqK[b * Cn + h * 64 + lane]), 1e-12f);
  for (int i = 0; i < 16; ++i) {
    int d = w * 16 + i;
    float rqd = 1.0f / fmaxf(sqrtf(sqQ[b * Cn + h * 64 + d]), 1e-12f);
    float v = Praw[(size_t)bh * 4096 + d * 64 + lane] * (rqd * rk * 0.125f);
    float m = v;
    for (int o = 32; o > 0; o >>= 1) m = fmaxf(m, __shfl_xor(m, o, 64));
    float p = __expf(v - m);
    float s = p;
    for (int o = 32; o > 0; o >>= 1) s += __shfl_xor(s, o, 64);
    P3[lane * 66 + d] = p / s;  // transposed: [e][d]
  }
  __syncthreads();
  {
    int e = t >> 2, dg = (t & 3) * 16;
    u16x8 o0, o1;
#pragma unroll
    for (int j = 0; j < 8; ++j) {
      o0[j] = f2b(P3[e * 66 + dg + j]);
      o1[j] = f2b(P3[e * 66 + dg + 8 + j]);
    }
    size_t base = (size_t)bh * 4096 + e * 64 + dg;
    *(u16x8*)&PT[base] = o0;
    *(u16x8*)&PT[base + 8] = o1;
  }
}

// weight prep: bf16 converts (packed WQKV + WO) and transposed W1T/W2T in one kernel
__global__ void k_prep(const float* __restrict__ wq, const float* __restrict__ wk,
                       const float* __restrict__ wv, const float* __restrict__ wo,
                       const float* __restrict__ w1, const float* __restrict__ w2,
                       unsigned short* __restrict__ WQKV, unsigned short* __restrict__ WO,
                       unsigned short* __restrict__ W1T, unsigned short* __restrict__ W2T) {
  int bid = blockIdx.x;
  if (bid < 1024) {
    const int mat = bid >> 8, chunk = bid & 255;
    const float* s = mat == 0 ? wq : mat == 1 ? wk : mat == 2 ? wv : wo;
    unsigned short* d = mat == 3 ? WO : (WQKV + mat * 262144);
    int idx = chunk * 1024 + threadIdx.x * 4;
    f32x4 v = *(const f32x4*)(s + idx);
    u16x4 o = {f2b(v[0]), f2b(v[1]), f2b(v[2]), f2b(v[3])};
    *(u16x4*)(d + idx) = o;
    return;
  }
  bid -= 1024;
  __shared__ float tile[32][33];
  const float* src; unsigned short* dst; int R, C, r0, c0;
  if (bid < 512) { src = w1; dst = W1T; R = 512; C = 1024; r0 = (bid >> 5) * 32; c0 = (bid & 31) * 32; }
  else { bid -= 512; src = w2; dst = W2T; R = 1024; C = 512; r0 = (bid >> 4) * 32; c0 = (bid & 15) * 32; }
  const int tx = threadIdx.x & 31, ty = threadIdx.x >> 5;
#pragma unroll
  for (int i = 0; i < 4; ++i)
    tile[ty + i * 8][tx] = src[(size_t)(r0 + ty + i * 8) * C + c0 + tx];
  __syncthreads();
#pragma unroll
  for (int i = 0; i < 4; ++i)
    dst[(size_t)(c0 + ty + i * 8) * R + r0 + tx] = f2b(tile[tx][ty + i * 8]);
}

extern "C" void kernel_launch(void* const* d_in, const int* in_sizes, int n_in,
                              void* d_out, int out_size, void* d_ws, size_t ws_size,
                              hipStream_t stream) {
  const float* x_opt = (const float*)d_in[0];
  const float* x_sar = (const float*)d_in[1];
  const float* ln_o_w = (const float*)d_in[2];
  const float* ln_o_b = (const float*)d_in[3];
  const float* ln_s_w = (const float*)d_in[4];
  const float* ln_s_b = (const float*)d_in[5];
  const float* wq = (const float*)d_in[6];
  const float* bq = (const float*)d_in[7];
  const float* wk = (const float*)d_in[8];
  const float* bk = (const float*)d_in[9];
  const float* wv = (const float*)d_in[10];
  const float* bv = (const float*)d_in[11];
  const float* w1 = (const float*)d_in[12];
  const float* b1 = (const float*)d_in[13];
  const float* w2 = (const float*)d_in[14];
  const float* b2 = (const float*)d_in[15];
  const float* wo = (const float*)d_in[16];
  const float* bo = (const float*)d_in[17];
  float* out = (float*)d_out;

  char* ws = (char*)d_ws;
  const size_t S = (size_t)Mtot * Cn * 2;  // 33,554,432
  unsigned short* XO = (unsigned short*)(ws);
  unsigned short* XS = (unsigned short*)(ws + S);
  unsigned short* Qb = (unsigned short*)(ws + 2 * S);
  unsigned short* KVb = (unsigned short*)(ws + 3 * S);  // [32768][1024]: K cols 0-511, V 512-1023
  unsigned short* ZS = (unsigned short*)(ws + 5 * S);
  unsigned short* H1 = Qb;  // alias: [2S,4S) — Q and K/V dead after attention
  unsigned short* Ub = XS;  // alias: XS dead after KV GEMM
  char* E = ws + 6 * S;
  unsigned short* PT = (unsigned short*)(E);                       // 524288
  float* Praw = (float*)(E + 524288);                              // 1048576
  float* sqQ = (float*)(E + 524288 + 1048576);                     // 16384
  float* sqK = (float*)(E + 524288 + 1048576 + 16384);             // 16384
  float* meanG = (float*)(E + 524288 + 1048576 + 32768);           // 131072
  float* rstdG = (float*)(E + 524288 + 1048576 + 32768 + 131072);  // 131072
  char* Wb = E + 1867776;
  unsigned short* WQKV = (unsigned short*)(Wb);          // [1536][512] packed Q,K,V
  unsigned short* WO = (unsigned short*)(Wb + 1572864);
  unsigned short* W1T = (unsigned short*)(Wb + 2097152);
  unsigned short* W2T = (unsigned short*)(Wb + 2097152 + 1048576);

  // zero the atomic targets (Praw, sqQ, sqK are contiguous)
  hipMemsetAsync(E + 524288, 0, 1048576 + 32768, stream);

  k_prep<<<2048, 256, 0, stream>>>(wq, wk, wv, wo, w1, w2, WQKV, WO, W1T, W2T);

  k_ln<<<dim3(128, Bn, 2), 256, 0, stream>>>(x_opt, x_sar, ln_o_w, ln_o_b, ln_s_w, ln_s_b,
                                             XO, XS, meanG, rstdG);

  // QKV: 128x256 tiles, N=1536 -> 6 n-tiles
  k_gw<0><<<dim3(6, 256), 512, 0, stream>>>(XO, XS, WQKV, bq, bk, bv, nullptr,
                                            Qb, KVb, 512, 1536, sqQ, sqK);

  k_attn_part<<<dim3(64, 8), 256, 0, stream>>>(Qb, 512, KVb, 1024, Praw);
  k_softmax<<<64, 256, 0, stream>>>(Praw, sqQ, sqK, PT);
  k_z<<<dim3(32, 64), 256, 0, stream>>>(KVb + 512, 1024, PT, XO, ZS);

  k_gw<1><<<dim3(4, 256), 512, 0, stream>>>(ZS, nullptr, W1T, b1, nullptr, nullptr, nullptr,
                                            H1, nullptr, 512, 1024, nullptr, nullptr);
  k_gw<2><<<dim3(2, 256), 512, 0, stream>>>(H1, nullptr, W2T, b2, nullptr, nullptr, ZS,
                                            Ub, nullptr, 1024, 512, nullptr, nullptr);
  k_gemm_out<<<256, 512, 0, stream>>>(WO, Ub, bo, x_opt, meanG, rstdG,
                                      ln_o_w, ln_o_b, out);
}

// Round 11
// 302.888 us; speedup vs baseline: 1.1375x; 1.1375x over previous
//
#include <hip/hip_runtime.h>
#include <cstdint>
#include <cstddef>

#define DEVI __device__ __forceinline__

typedef __attribute__((ext_vector_type(8))) short short8;
typedef __attribute__((ext_vector_type(4))) float f32x4;
typedef __attribute__((ext_vector_type(2))) unsigned short u16x2;
typedef __attribute__((ext_vector_type(4))) unsigned short u16x4;
typedef __attribute__((ext_vector_type(8))) unsigned short u16x8;

#define Bn 8
#define Cn 512
#define HWn 4096
#define Mtot 32768

DEVI float b2f(unsigned short u) {
  union { uint32_t u; float f; } c; c.u = ((uint32_t)u) << 16; return c.f;
}
DEVI unsigned short f2b(float f) {
  union { float f; uint32_t u; } c; c.f = f;
  uint32_t u = c.u + 0x7fffu + ((c.u >> 16) & 1u);
  return (unsigned short)(u >> 16);
}
// tanh-form gelu; |err| vs exact erf-gelu ~1e-3, well under bf16 output noise
DEVI float gelu_fast(float x) {
  float y = 0.7978845608f * (x + 0.044715f * x * x * x);
  float e = __expf(2.0f * y);
  float t = 1.0f - 2.0f / (e + 1.0f);
  return 0.5f * x * (1.0f + t);
}

DEVI void async16(const void* g, void* l) {
  __builtin_amdgcn_global_load_lds((const __attribute__((address_space(1))) uint32_t*)g,
                                   (__attribute__((address_space(3))) uint32_t*)l, 16, 0, 0);
}

// stage 128 rows x 64 k of bf16 into LDS (256-thread kernels).
// linear LDS dest (wave-uniform base + lane*16), XOR-pre-swizzled global source.
DEVI void stage128(const unsigned short* __restrict__ src, int ld, int row0, int kt,
                   char* lds, int t) {
  const int w = t >> 6;
  const int srow = t >> 3, sph = t & 7;
#pragma unroll
  for (int i = 0; i < 4; ++i) {
    int row = i * 32 + srow;
    int slog = sph ^ (row & 7);
    async16(src + (size_t)(row0 + row) * ld + kt + slog * 8, lds + i * 4096 + w * 1024);
  }
}

// stage 256 rows x 64 k (512-thread k_gemm_out)
DEVI void stage256(const unsigned short* __restrict__ src, int ld, int row0, int kt,
                   char* lds, int t) {
  const int w = t >> 6;
  const int srow = t >> 3, sph = t & 7;
#pragma unroll
  for (int i = 0; i < 4; ++i) {
    int row = i * 64 + srow;
    int slog = sph ^ (row & 7);
    async16(src + (size_t)(row0 + row) * ld + kt + slog * 8, lds + i * 8192 + w * 1024);
  }
}

// one K=64 compute step (2 x k32, 32 MFMA total); As/Bs row stride 64, slot-XOR swizzle
DEVI void gemm_compute(const unsigned short* As, const unsigned short* Bs,
                       int wr, int wc, int l15, int l4, f32x4 (&acc)[4][4]) {
#pragma unroll
  for (int ks = 0; ks < 2; ++ks) {
    short8 af[4], bfv[4];
#pragma unroll
    for (int m = 0; m < 4; ++m) {
      int row = wr * 64 + m * 16 + l15;
      int slog = ks * 4 + l4;
      af[m] = *(const short8*)&As[row * 64 + ((slog ^ (row & 7)) << 3)];
    }
#pragma unroll
    for (int n = 0; n < 4; ++n) {
      int row = wc * 64 + n * 16 + l15;
      int slog = ks * 4 + l4;
      bfv[n] = *(const short8*)&Bs[row * 64 + ((slog ^ (row & 7)) << 3)];
    }
#pragma unroll
    for (int m = 0; m < 4; ++m)
#pragma unroll
      for (int n = 0; n < 4; ++n)
        acc[m][n] = __builtin_amdgcn_mfma_f32_16x16x32_bf16(af[m], bfv[n], acc[m][n], 0, 0, 0);
  }
}

// Fused Q/K/V projection GEMM: A = XO (n-tiles 0-3) or XS (4-11); W = WQKV [1536][512].
// 128x128 tile, 256 threads, single-buffered, 4 blocks/CU. XCD-chunked swizzle.
// Epilogue: bias, col sq-norm atomics (Q,K only), bf16 stash, coalesced store.
__global__ __launch_bounds__(256, 4) void k_qkv(
    const unsigned short* __restrict__ XO, const unsigned short* __restrict__ XS,
    const unsigned short* __restrict__ WQKV,
    const float* __restrict__ bq, const float* __restrict__ bk, const float* __restrict__ bv,
    unsigned short* __restrict__ Qb, unsigned short* __restrict__ KVb,
    float* __restrict__ sqQ, float* __restrict__ sqK) {
  __shared__ __align__(16) char smem[33792];
  unsigned short* As = (unsigned short*)smem;
  unsigned short* Bs = (unsigned short*)(smem + 16384);
  const int lin = blockIdx.x + 12 * blockIdx.y;
  const int xcd = lin & 7, j = lin >> 3;
  const int mt = xcd * 32 + j / 12;
  const int nt = j % 12;
  const int m0 = mt * 128, n0 = nt * 128;
  const unsigned short* A = (nt < 4) ? XO : XS;
  const float* bb = (nt < 4) ? (bq + n0) : (nt < 8 ? (bk + (nt - 4) * 128) : (bv + (nt - 8) * 128));
  float* sq = (nt < 4) ? sqQ : (nt < 8 ? sqK : nullptr);
  const int scol0 = (nt < 4) ? n0 : (nt - 4) * 128;
  unsigned short* ob = (nt < 4) ? Qb : KVb;
  const int ldo = (nt < 4) ? 512 : 1024;
  const int oc0 = (nt < 4) ? n0 : (nt - 4) * 128;
  const int t = threadIdx.x, w = t >> 6, lane = t & 63;
  const int wr = w >> 1, wc = w & 1, l15 = lane & 15, l4 = lane >> 4;
  f32x4 acc[4][4] = {};

  for (int kt = 0; kt < 512; kt += 64) {
    stage128(A, 512, m0, kt, (char*)As, t);
    stage128(WQKV, 512, n0, kt, (char*)Bs, t);
    __syncthreads();
    gemm_compute(As, Bs, wr, wc, l15, l4, acc);
    __syncthreads();
  }

  unsigned short* Cs = (unsigned short*)smem;  // [128][132] stash
#pragma unroll
  for (int n = 0; n < 4; ++n) {
    int cn = wc * 64 + n * 16 + l15;
    float bn = bb[cn];
    float s2 = 0.f;
#pragma unroll
    for (int m = 0; m < 4; ++m) {
      int rb = wr * 64 + m * 16 + l4 * 4;
#pragma unroll
      for (int q = 0; q < 4; ++q) {
        float v = acc[m][n][q] + bn;
        s2 += v * v;
        Cs[(rb + q) * 132 + cn] = f2b(v);
      }
    }
    if (sq) {
      s2 += __shfl_xor(s2, 16, 64);
      s2 += __shfl_xor(s2, 32, 64);
      if (l4 == 0) atomicAdd(&sq[(m0 >> 12) * Cn + scol0 + cn], s2);
    }
  }
  __syncthreads();
#pragma unroll
  for (int pass = 0; pass < 4; ++pass) {
    int r = pass * 32 + (t >> 3);
    int c = (t & 7) * 8;
    u16x8 v0 = *(const u16x8*)&Cs[r * 132 + c];
    u16x8 v1 = *(const u16x8*)&Cs[r * 132 + 64 + c];
    size_t base = (size_t)(m0 + r) * ldo + oc0;
    *(u16x8*)&ob[base + c] = v0;
    *(u16x8*)&ob[base + 64 + c] = v1;
  }
}

// FFN GEMMs. MODE 1: gelu(acc+bias). MODE 2: acc+bias+res.
// 128x128 tile, 256 threads, single-buffered, 4 blocks/CU. XCD-chunked swizzle.
template <int MODE>
__global__ __launch_bounds__(256, 4) void k_ffn(
    const unsigned short* __restrict__ A, const unsigned short* __restrict__ W,
    const float* __restrict__ bias, const unsigned short* __restrict__ res,
    unsigned short* __restrict__ out, int K, int N) {
  __shared__ __align__(16) char smem[33792];
  unsigned short* As = (unsigned short*)smem;
  unsigned short* Bs = (unsigned short*)(smem + 16384);
  const int NT = gridDim.x;
  const int lin = blockIdx.x + NT * blockIdx.y;
  const int xcd = lin & 7, j = lin >> 3;
  const int mt = xcd * 32 + j / NT;
  const int nt = j % NT;
  const int m0 = mt * 128, n0 = nt * 128;
  const int t = threadIdx.x, w = t >> 6, lane = t & 63;
  const int wr = w >> 1, wc = w & 1, l15 = lane & 15, l4 = lane >> 4;
  f32x4 acc[4][4] = {};

  for (int kt = 0; kt < K; kt += 64) {
    stage128(A, K, m0, kt, (char*)As, t);
    stage128(W, K, n0, kt, (char*)Bs, t);
    __syncthreads();
    gemm_compute(As, Bs, wr, wc, l15, l4, acc);
    __syncthreads();
  }

  unsigned short* Cs = (unsigned short*)smem;  // [128][132] stash
#pragma unroll
  for (int n = 0; n < 4; ++n) {
    int cn = wc * 64 + n * 16 + l15;
    float bn = bias[n0 + cn];
#pragma unroll
    for (int m = 0; m < 4; ++m) {
      int rb = wr * 64 + m * 16 + l4 * 4;
#pragma unroll
      for (int q = 0; q < 4; ++q) {
        float v = acc[m][n][q] + bn;
        if (MODE == 1) v = gelu_fast(v);
        Cs[(rb + q) * 132 + cn] = f2b(v);
      }
    }
  }
  __syncthreads();
#pragma unroll
  for (int pass = 0; pass < 4; ++pass) {
    int r = pass * 32 + (t >> 3);
    int c = (t & 7) * 8;
    u16x8 v0 = *(const u16x8*)&Cs[r * 132 + c];
    u16x8 v1 = *(const u16x8*)&Cs[r * 132 + 64 + c];
    size_t base = (size_t)(m0 + r) * N + n0;
    if (MODE == 2) {
      u16x8 r0 = *(const u16x8*)&res[base + c];
      u16x8 r1 = *(const u16x8*)&res[base + 64 + c];
#pragma unroll
      for (int jj = 0; jj < 8; ++jj) {
        v0[jj] = f2b(b2f(v0[jj]) + b2f(r0[jj]));
        v1[jj] = f2b(b2f(v1[jj]) + b2f(r1[jj]));
      }
    }
    *(u16x8*)&out[base + c] = v0;
    *(u16x8*)&out[base + 64 + c] = v1;
  }
}

// one K=64 compute step for the 256x256 tile: 8 waves (2M x 4N), per-wave 128x64 out.
DEVI void compute256(const unsigned short* Ab, const unsigned short* Bb,
                     int wr, int wc, int l15, int l4, f32x4 (&acc)[8][4]) {
#pragma unroll
  for (int ks = 0; ks < 2; ++ks) {
    short8 aF[8], bF[4];
#pragma unroll
    for (int mf = 0; mf < 8; ++mf) {
      int row = wr * 128 + mf * 16 + l15;
      aF[mf] = *(const short8*)&Ab[row * 64 + (((ks * 4 + l4) ^ (row & 7)) << 3)];
    }
#pragma unroll
    for (int nf = 0; nf < 4; ++nf) {
      int row = wc * 64 + nf * 16 + l15;
      bF[nf] = *(const short8*)&Bb[row * 64 + (((ks * 4 + l4) ^ (row & 7)) << 3)];
    }
#pragma unroll
    for (int mf = 0; mf < 8; ++mf)
#pragma unroll
      for (int nf = 0; nf < 4; ++nf)
        acc[mf][nf] = __builtin_amdgcn_mfma_f32_16x16x32_bf16(aF[mf], bF[nf], acc[mf][nf], 0, 0, 0);
  }
}

// Final: out[b,c,n] = wo@U + bo + xo. 256x256 tile, 2-phase dbuf, coalesced fp32 epilogue.
__global__ __launch_bounds__(512, 2) void k_gemm_out(
    const unsigned short* __restrict__ Wo, const unsigned short* __restrict__ U,
    const float* __restrict__ bo, const float* __restrict__ xopt,
    const float* __restrict__ meanG, const float* __restrict__ rstdG,
    const float* __restrict__ lnw, const float* __restrict__ lnb,
    float* __restrict__ out) {
  __shared__ __align__(16) char smem[131072];
  const int lin = blockIdx.x;
  const int xcd = lin & 7, j = lin >> 3;
  const int b = xcd, mt = j & 1, nt = j >> 1;
  const int m0 = mt * 256, n0 = nt * 256;
  const unsigned short* Ub = U + (size_t)b * HWn * Cn;
  const int t = threadIdx.x, lane = t & 63;
  const int w = t >> 6, wr = w >> 2, wc = w & 3;
  const int l15 = lane & 15, l4 = lane >> 4;
  f32x4 acc[8][4] = {};

  stage256(Wo, 512, m0, 0, smem, t);
  stage256(Ub, 512, n0, 0, smem + 32768, t);
  __syncthreads();
  for (int kt = 0; kt < 8; ++kt) {
    if (kt + 1 < 8) {
      char* nb = smem + ((kt + 1) & 1) * 65536;
      stage256(Wo, 512, m0, (kt + 1) * 64, nb, t);
      stage256(Ub, 512, n0, (kt + 1) * 64, nb + 32768, t);
    }
    const unsigned short* Ab = (const unsigned short*)(smem + (kt & 1) * 65536);
    const unsigned short* Bb = (const unsigned short*)(smem + (kt & 1) * 65536 + 32768);
    compute256(Ab, Bb, wr, wc, l15, l4, acc);
    __syncthreads();
  }

  float* Fs = (float*)smem;  // [64][260] f32 stash, four c-quarters
#pragma unroll
  for (int qd = 0; qd < 4; ++qd) {
    __syncthreads();
    if (wr == (qd >> 1)) {
#pragma unroll
      for (int nf = 0; nf < 4; ++nf) {
        int cn = wc * 64 + nf * 16 + l15;
#pragma unroll
        for (int mf2 = 0; mf2 < 4; ++mf2) {
          int mf = (qd & 1) * 4 + mf2;
#pragma unroll
          for (int q = 0; q < 4; ++q)
            Fs[(mf2 * 16 + l4 * 4 + q) * 260 + cn] = acc[mf][nf][q];
        }
      }
    }
    __syncthreads();
#pragma unroll
    for (int p = 0; p < 8; ++p) {
      int cl = p * 8 + w;            // wave-uniform channel row within quarter
      int px = lane * 4;             // 4 contiguous pixels per lane -> 1KB/wave
      int c = m0 + qd * 64 + cl;
      size_t gbase = (size_t)(b * Cn + c) * HWn + n0 + px;
      f32x4 z = *(const f32x4*)&Fs[cl * 260 + px];
      f32x4 xv = *(const f32x4*)&xopt[gbase];
      f32x4 mn4 = *(const f32x4*)&meanG[b * HWn + n0 + px];
      f32x4 rs4 = *(const f32x4*)&rstdG[b * HWn + n0 + px];
      float lw = lnw[c], lb = lnb[c], bc = bo[c];
      f32x4 o;
#pragma unroll
      for (int jj = 0; jj < 4; ++jj)
        o[jj] = z[jj] + bc + (xv[jj] - mn4[jj]) * rs4[jj] * lw + lb;
      *(f32x4*)&out[gbase] = o;
    }
  }
}

// Z = V_head @ P  (M=128 pixels, N=64, K=64), epilogue adds z_opt (= XO, same layout)
__global__ __launch_bounds__(256, 2) void k_z(
    const unsigned short* __restrict__ V, int ldv, const unsigned short* __restrict__ PT,
    const unsigned short* __restrict__ XO, unsigned short* __restrict__ ZS) {
  __shared__ __align__(16) char smem[24576];
  unsigned short* As = (unsigned short*)smem;
  unsigned short* Bs = (unsigned short*)(smem + 16384);
  const int mt = blockIdx.x, bh = blockIdx.y, b = bh >> 3, h = bh & 7;
  const int t = threadIdx.x, w = t >> 6, lane = t & 63;
  const int wr = w >> 1, wc = w & 1, l15 = lane & 15, l4 = lane >> 4;
  const int srow = t >> 3, sph = t & 7;
#pragma unroll
  for (int i = 0; i < 4; ++i) {
    int row = i * 32 + srow;
    int slog = sph ^ (row & 7);
    async16(V + (size_t)(b * HWn + mt * 128 + row) * ldv + h * 64 + slog * 8,
            (char*)As + i * 4096 + w * 1024);
  }
#pragma unroll
  for (int i = 0; i < 2; ++i) {
    int row = i * 32 + srow;
    int slog = sph ^ (row & 7);
    async16(PT + (size_t)bh * 4096 + row * 64 + slog * 8, (char*)Bs + i * 4096 + w * 1024);
  }
  __syncthreads();
  f32x4 acc[4][2] = {};
#pragma unroll
  for (int ks = 0; ks < 2; ++ks) {
    short8 af[4], bfv[2];
#pragma unroll
    for (int m = 0; m < 4; ++m) {
      int row = wr * 64 + m * 16 + l15;
      int slog = ks * 4 + l4;
      af[m] = *(const short8*)&As[row * 64 + ((slog ^ (row & 7)) << 3)];
    }
#pragma unroll
    for (int n = 0; n < 2; ++n) {
      int row = wc * 32 + n * 16 + l15;
      int slog = ks * 4 + l4;
      bfv[n] = *(const short8*)&Bs[row * 64 + ((slog ^ (row & 7)) << 3)];
    }
#pragma unroll
    for (int m = 0; m < 4; ++m)
#pragma unroll
      for (int n = 0; n < 2; ++n)
        acc[m][n] = __builtin_amdgcn_mfma_f32_16x16x32_bf16(af[m], bfv[n], acc[m][n], 0, 0, 0);
  }
  __syncthreads();
  unsigned short* Cs = (unsigned short*)smem;  // [128][72]
#pragma unroll
  for (int n = 0; n < 2; ++n) {
    int e = wc * 32 + n * 16 + l15;
#pragma unroll
    for (int m = 0; m < 4; ++m) {
      int rb = wr * 64 + m * 16 + l4 * 4;
#pragma unroll
      for (int q = 0; q < 4; ++q) Cs[(rb + q) * 72 + e] = f2b(acc[m][n][q]);
    }
  }
  __syncthreads();
#pragma unroll
  for (int pass = 0; pass < 4; ++pass) {
    int r = pass * 32 + (t >> 3);
    int c = (t & 7) * 8;
    u16x8 v = *(const u16x8*)&Cs[r * 72 + c];
    size_t idx = (size_t)(b * HWn + mt * 128 + r) * Cn + h * 64 + c;
    u16x8 xo = *(const u16x8*)&XO[idx];
#pragma unroll
    for (int jj = 0; jj < 8; ++jj) v[jj] = f2b(b2f(v[jj]) + b2f(xo[jj]));
    *(u16x8*)&ZS[idx] = v;
  }
}

// LayerNorm over C per pixel; writes transposed bf16 [pixel, C]. z=0: x_opt(+stats); z=1: x_sar.
__global__ __launch_bounds__(256, 2) void k_ln(
    const float* __restrict__ x_opt, const float* __restrict__ x_sar,
    const float* __restrict__ lwo, const float* __restrict__ lbo,
    const float* __restrict__ lws, const float* __restrict__ lbs,
    unsigned short* __restrict__ XO, unsigned short* __restrict__ XS,
    float* __restrict__ meanG, float* __restrict__ rstdG) {
  const int zz = blockIdx.z;
  const float* x = zz ? x_sar : x_opt;
  const float* lw = zz ? lws : lwo;
  const float* lb = zz ? lbs : lbo;
  unsigned short* out = zz ? XS : XO;
  __shared__ unsigned short stash[512 * 34];
  __shared__ float redS[256 * 4], redQ[256 * 4];
  __shared__ float meanS[32], rstdS[32], wS[512], bS[512];
  const int b = blockIdx.y, n0 = blockIdx.x * 32;
  const int t = threadIdx.x;
  wS[t] = lw[t]; wS[t + 256] = lw[t + 256];
  bS[t] = lb[t]; bS[t + 256] = lb[t + 256];
  const int cg = t >> 3, pq = t & 7;
  float sum[4] = {}, sq[4] = {};
  for (int r = 0; r < 16; ++r) {
    int c = r * 32 + cg;
    f32x4 v = *(const f32x4*)(x + (size_t)(b * Cn + c) * HWn + n0 + pq * 4);
#pragma unroll
    for (int j = 0; j < 4; ++j) { sum[j] += v[j]; sq[j] += v[j] * v[j]; }
    u16x2 h0 = {f2b(v[0]), f2b(v[1])};
    u16x2 h1 = {f2b(v[2]), f2b(v[3])};
    *(u16x2*)&stash[c * 34 + pq * 4] = h0;
    *(u16x2*)&stash[c * 34 + pq * 4 + 2] = h1;
  }
#pragma unroll
  for (int j = 0; j < 4; ++j) { redS[t * 4 + j] = sum[j]; redQ[t * 4 + j] = sq[j]; }
  __syncthreads();
  if (t < 32) {
    float s = 0.f, qq = 0.f;
    int pqq = t >> 2, j = t & 3;
    for (int g = 0; g < 32; ++g) {
      s += redS[(g * 8 + pqq) * 4 + j];
      qq += redQ[(g * 8 + pqq) * 4 + j];
    }
    float mean = s * (1.0f / 512.0f);
    float var = qq * (1.0f / 512.0f) - mean * mean;
    float rstd = rsqrtf(var + 1e-5f);
    meanS[t] = mean; rstdS[t] = rstd;
    if (!zz) { meanG[b * HWn + n0 + t] = mean; rstdG[b * HWn + n0 + t] = rstd; }
  }
  __syncthreads();
  const int p = t >> 3, cs = t & 7;
  float mn = meanS[p], rs = rstdS[p];
  for (int ch = 0; ch < 4; ++ch) {
    u16x8 o0, o1;
#pragma unroll
    for (int j = 0; j < 16; ++j) {
      int c = ch * 128 + cs * 16 + j;
      float xv = b2f(stash[c * 34 + p]);
      unsigned short r2 = f2b((xv - mn) * rs * wS[c] + bS[c]);
      if (j < 8) o0[j] = r2; else o1[j - 8] = r2;
    }
    size_t base = (size_t)(b * HWn + n0 + p) * Cn + ch * 128 + cs * 16;
    *(u16x8*)&out[base] = o0;
    *(u16x8*)&out[base + 8] = o1;
  }
}

// MFMA partial Gram over a 512-row slice: Praw[bh][d][e] += sum_n Q[n,d]*K[n,e].
__global__ __launch_bounds__(256, 2) void k_attn_part(
    const unsigned short* __restrict__ Q, int ldq,
    const unsigned short* __restrict__ Kb, int ldk,
    float* __restrict__ Praw) {
  __shared__ __align__(16) unsigned short QT[64 * 136];
  __shared__ __align__(16) unsigned short KT[64 * 136];
  const int bh = blockIdx.x, ns = blockIdx.y, b = bh >> 3, h = bh & 7;
  const int t = threadIdx.x, w = t >> 6, lane = t & 63;
  const int l15 = lane & 15, l4 = lane >> 4;
  const int dh = w >> 1, eh = w & 1;
  const int c8 = t >> 5, rr = t & 31;
  f32x4 acc[2][2] = {};
  for (int chunk = 0; chunk < 4; ++chunk) {
    int n0 = ns * 512 + chunk * 128;
    __syncthreads();
#pragma unroll
    for (int pass = 0; pass < 2; ++pass) {
      int row = n0 + pass * 64 + 2 * rr;
      u16x8 q0 = *(const u16x8*)(Q + (size_t)(b * HWn + row) * ldq + h * 64 + c8 * 8);
      u16x8 q1 = *(const u16x8*)(Q + (size_t)(b * HWn + row + 1) * ldq + h * 64 + c8 * 8);
      u16x8 k0 = *(const u16x8*)(Kb + (size_t)(b * HWn + row) * ldk + h * 64 + c8 * 8);
      u16x8 k1 = *(const u16x8*)(Kb + (size_t)(b * HWn + row + 1) * ldk + h * 64 + c8 * 8);
#pragma unroll
      for (int j = 0; j < 8; ++j) {
        u16x2 pq = {q0[j], q1[j]};
        u16x2 pk = {k0[j], k1[j]};
        *(u16x2*)&QT[(c8 * 8 + j) * 136 + pass * 64 + 2 * rr] = pq;
        *(u16x2*)&KT[(c8 * 8 + j) * 136 + pass * 64 + 2 * rr] = pk;
      }
    }
    __syncthreads();
#pragma unroll
    for (int ks = 0; ks < 4; ++ks) {
      short8 af[2], bfv[2];
#pragma unroll
      for (int m = 0; m < 2; ++m)
        af[m] = *(const short8*)&QT[(dh * 32 + m * 16 + l15) * 136 + ks * 32 + l4 * 8];
#pragma unroll
      for (int n = 0; n < 2; ++n)
        bfv[n] = *(const short8*)&KT[(eh * 32 + n * 16 + l15) * 136 + ks * 32 + l4 * 8];
#pragma unroll
      for (int m = 0; m < 2; ++m)
#pragma unroll
        for (int n = 0; n < 2; ++n)
          acc[m][n] = __builtin_amdgcn_mfma_f32_16x16x32_bf16(af[m], bfv[n], acc[m][n], 0, 0, 0);
    }
  }
#pragma unroll
  for (int m = 0; m < 2; ++m)
#pragma unroll
    for (int n = 0; n < 2; ++n)
#pragma unroll
      for (int q = 0; q < 4; ++q) {
        int dd = dh * 32 + m * 16 + l4 * 4 + q;
        int ee = eh * 32 + n * 16 + l15;
        atomicAdd(&Praw[(size_t)bh * 4096 + dd * 64 + ee], acc[m][n][q]);
      }
}

// scale by rq*rk/8, row softmax, store PT[bh][e][d] bf16 (layout k_z consumes)
__global__ __launch_bounds__(256, 2) void k_softmax(
    const float* __restrict__ Praw, const float* __restrict__ sqQ,
    const float* __restrict__ sqK, unsigned short* __restrict__ PT) {
  __shared__ float P3[64 * 66];
  const int bh = blockIdx.x, b = bh >> 3, h = bh & 7;
  const int t = threadIdx.x, w = t >> 6, lane = t & 63;
  float rk = 1.0f / fmaxf(sqrtf(sqK[b * Cn + h * 64 + lane]), 1e-12f);
  for (int i = 0; i < 16; ++i) {
    int d = w * 16 + i;
    float rqd = 1.0f / fmaxf(sqrtf(sqQ[b * Cn + h * 64 + d]), 1e-12f);
    float v = Praw[(size_t)bh * 4096 + d * 64 + lane] * (rqd * rk * 0.125f);
    float m = v;
    for (int o = 32; o > 0; o >>= 1) m = fmaxf(m, __shfl_xor(m, o, 64));
    float p = __expf(v - m);
    float s = p;
    for (int o = 32; o > 0; o >>= 1) s += __shfl_xor(s, o, 64);
    P3[lane * 66 + d] = p / s;  // transposed: [e][d]
  }
  __syncthreads();
  {
    int e = t >> 2, dg = (t & 3) * 16;
    u16x8 o0, o1;
#pragma unroll
    for (int j = 0; j < 8; ++j) {
      o0[j] = f2b(P3[e * 66 + dg + j]);
      o1[j] = f2b(P3[e * 66 + dg + 8 + j]);
    }
    size_t base = (size_t)bh * 4096 + e * 64 + dg;
    *(u16x8*)&PT[base] = o0;
    *(u16x8*)&PT[base + 8] = o1;
  }
}

// weight prep: bf16 converts (packed WQKV + WO) and transposed W1T/W2T in one kernel
__global__ void k_prep(const float* __restrict__ wq, const float* __restrict__ wk,
                       const float* __restrict__ wv, const float* __restrict__ wo,
                       const float* __restrict__ w1, const float* __restrict__ w2,
                       unsigned short* __restrict__ WQKV, unsigned short* __restrict__ WO,
                       unsigned short* __restrict__ W1T, unsigned short* __restrict__ W2T) {
  int bid = blockIdx.x;
  if (bid < 1024) {
    const int mat = bid >> 8, chunk = bid & 255;
    const float* s = mat == 0 ? wq : mat == 1 ? wk : mat == 2 ? wv : wo;
    unsigned short* d = mat == 3 ? WO : (WQKV + mat * 262144);
    int idx = chunk * 1024 + threadIdx.x * 4;
    f32x4 v = *(const f32x4*)(s + idx);
    u16x4 o = {f2b(v[0]), f2b(v[1]), f2b(v[2]), f2b(v[3])};
    *(u16x4*)(d + idx) = o;
    return;
  }
  bid -= 1024;
  __shared__ float tile[32][33];
  const float* src; unsigned short* dst; int R, C, r0, c0;
  if (bid < 512) { src = w1; dst = W1T; R = 512; C = 1024; r0 = (bid >> 5) * 32; c0 = (bid & 31) * 32; }
  else { bid -= 512; src = w2; dst = W2T; R = 1024; C = 512; r0 = (bid >> 4) * 32; c0 = (bid & 15) * 32; }
  const int tx = threadIdx.x & 31, ty = threadIdx.x >> 5;
#pragma unroll
  for (int i = 0; i < 4; ++i)
    tile[ty + i * 8][tx] = src[(size_t)(r0 + ty + i * 8) * C + c0 + tx];
  __syncthreads();
#pragma unroll
  for (int i = 0; i < 4; ++i)
    dst[(size_t)(c0 + ty + i * 8) * R + r0 + tx] = f2b(tile[tx][ty + i * 8]);
}

extern "C" void kernel_launch(void* const* d_in, const int* in_sizes, int n_in,
                              void* d_out, int out_size, void* d_ws, size_t ws_size,
                              hipStream_t stream) {
  const float* x_opt = (const float*)d_in[0];
  const float* x_sar = (const float*)d_in[1];
  const float* ln_o_w = (const float*)d_in[2];
  const float* ln_o_b = (const float*)d_in[3];
  const float* ln_s_w = (const float*)d_in[4];
  const float* ln_s_b = (const float*)d_in[5];
  const float* wq = (const float*)d_in[6];
  const float* bq = (const float*)d_in[7];
  const float* wk = (const float*)d_in[8];
  const float* bk = (const float*)d_in[9];
  const float* wv = (const float*)d_in[10];
  const float* bv = (const float*)d_in[11];
  const float* w1 = (const float*)d_in[12];
  const float* b1 = (const float*)d_in[13];
  const float* w2 = (const float*)d_in[14];
  const float* b2 = (const float*)d_in[15];
  const float* wo = (const float*)d_in[16];
  const float* bo = (const float*)d_in[17];
  float* out = (float*)d_out;

  char* ws = (char*)d_ws;
  const size_t S = (size_t)Mtot * Cn * 2;  // 33,554,432
  unsigned short* XO = (unsigned short*)(ws);
  unsigned short* XS = (unsigned short*)(ws + S);
  unsigned short* Qb = (unsigned short*)(ws + 2 * S);
  unsigned short* KVb = (unsigned short*)(ws + 3 * S);  // [32768][1024]: K cols 0-511, V 512-1023
  unsigned short* ZS = (unsigned short*)(ws + 5 * S);
  unsigned short* H1 = Qb;  // alias: [2S,4S) — Q and K/V dead after attention
  unsigned short* Ub = XS;  // alias: XS dead after KV GEMM
  char* E = ws + 6 * S;
  unsigned short* PT = (unsigned short*)(E);                       // 524288
  float* Praw = (float*)(E + 524288);                              // 1048576
  float* sqQ = (float*)(E + 524288 + 1048576);                     // 16384
  float* sqK = (float*)(E + 524288 + 1048576 + 16384);             // 16384
  float* meanG = (float*)(E + 524288 + 1048576 + 32768);           // 131072
  float* rstdG = (float*)(E + 524288 + 1048576 + 32768 + 131072);  // 131072
  char* Wb = E + 1867776;
  unsigned short* WQKV = (unsigned short*)(Wb);          // [1536][512] packed Q,K,V
  unsigned short* WO = (unsigned short*)(Wb + 1572864);
  unsigned short* W1T = (unsigned short*)(Wb + 2097152);
  unsigned short* W2T = (unsigned short*)(Wb + 2097152 + 1048576);

  // zero the atomic targets (Praw, sqQ, sqK are contiguous)
  hipMemsetAsync(E + 524288, 0, 1048576 + 32768, stream);

  k_prep<<<2048, 256, 0, stream>>>(wq, wk, wv, wo, w1, w2, WQKV, WO, W1T, W2T);

  k_ln<<<dim3(128, Bn, 2), 256, 0, stream>>>(x_opt, x_sar, ln_o_w, ln_o_b, ln_s_w, ln_s_b,
                                             XO, XS, meanG, rstdG);

  k_qkv<<<dim3(12, 256), 256, 0, stream>>>(XO, XS, WQKV, bq, bk, bv, Qb, KVb, sqQ, sqK);

  k_attn_part<<<dim3(64, 8), 256, 0, stream>>>(Qb, 512, KVb, 1024, Praw);
  k_softmax<<<64, 256, 0, stream>>>(Praw, sqQ, sqK, PT);
  k_z<<<dim3(32, 64), 256, 0, stream>>>(KVb + 512, 1024, PT, XO, ZS);

  k_ffn<1><<<dim3(8, 256), 256, 0, stream>>>(ZS, W1T, b1, nullptr, H1, 512, 1024);
  k_ffn<2><<<dim3(4, 256), 256, 0, stream>>>(H1, W2T, b2, ZS, Ub, 1024, 512);
  k_gemm_out<<<256, 512, 0, stream>>>(WO, Ub, bo, x_opt, meanG, rstdG,
                                      ln_o_w, ln_o_b, out);
}

// Round 12
// 302.140 us; speedup vs baseline: 1.1404x; 1.0025x over previous
//
#include <hip/hip_runtime.h>
#include <cstdint>
#include <cstddef>

#define DEVI __device__ __forceinline__

typedef __attribute__((ext_vector_type(8))) short short8;
typedef __attribute__((ext_vector_type(4))) float f32x4;
typedef __attribute__((ext_vector_type(2))) unsigned short u16x2;
typedef __attribute__((ext_vector_type(4))) unsigned short u16x4;
typedef __attribute__((ext_vector_type(8))) unsigned short u16x8;

#define Bn 8
#define Cn 512
#define HWn 4096
#define Mtot 32768

DEVI float b2f(unsigned short u) {
  union { uint32_t u; float f; } c; c.u = ((uint32_t)u) << 16; return c.f;
}
DEVI unsigned short f2b(float f) {
  union { float f; uint32_t u; } c; c.f = f;
  uint32_t u = c.u + 0x7fffu + ((c.u >> 16) & 1u);
  return (unsigned short)(u >> 16);
}
// tanh-form gelu; |err| vs exact erf-gelu ~1e-3, well under bf16 output noise
DEVI float gelu_fast(float x) {
  float y = 0.7978845608f * (x + 0.044715f * x * x * x);
  float e = __expf(2.0f * y);
  float t = 1.0f - 2.0f / (e + 1.0f);
  return 0.5f * x * (1.0f + t);
}

DEVI void async16(const void* g, void* l) {
  __builtin_amdgcn_global_load_lds((const __attribute__((address_space(1))) uint32_t*)g,
                                   (__attribute__((address_space(3))) uint32_t*)l, 16, 0, 0);
}

// stage 128 rows x 64 k of bf16 into LDS (256-thread kernels).
// linear LDS dest (wave-uniform base + lane*16), XOR-pre-swizzled global source.
DEVI void stage128(const unsigned short* __restrict__ src, int ld, int row0, int kt,
                   char* lds, int t) {
  const int w = t >> 6;
  const int srow = t >> 3, sph = t & 7;
#pragma unroll
  for (int i = 0; i < 4; ++i) {
    int row = i * 32 + srow;
    int slog = sph ^ (row & 7);
    async16(src + (size_t)(row0 + row) * ld + kt + slog * 8, lds + i * 4096 + w * 1024);
  }
}

// stage 256 rows x 64 k (512-thread k_gemm_out)
DEVI void stage256(const unsigned short* __restrict__ src, int ld, int row0, int kt,
                   char* lds, int t) {
  const int w = t >> 6;
  const int srow = t >> 3, sph = t & 7;
#pragma unroll
  for (int i = 0; i < 4; ++i) {
    int row = i * 64 + srow;
    int slog = sph ^ (row & 7);
    async16(src + (size_t)(row0 + row) * ld + kt + slog * 8, lds + i * 8192 + w * 1024);
  }
}

// one K=64 compute step (2 x k32, 32 MFMA total); As/Bs row stride 64, slot-XOR swizzle
DEVI void gemm_compute(const unsigned short* As, const unsigned short* Bs,
                       int wr, int wc, int l15, int l4, f32x4 (&acc)[4][4]) {
#pragma unroll
  for (int ks = 0; ks < 2; ++ks) {
    short8 af[4], bfv[4];
#pragma unroll
    for (int m = 0; m < 4; ++m) {
      int row = wr * 64 + m * 16 + l15;
      int slog = ks * 4 + l4;
      af[m] = *(const short8*)&As[row * 64 + ((slog ^ (row & 7)) << 3)];
    }
#pragma unroll
    for (int n = 0; n < 4; ++n) {
      int row = wc * 64 + n * 16 + l15;
      int slog = ks * 4 + l4;
      bfv[n] = *(const short8*)&Bs[row * 64 + ((slog ^ (row & 7)) << 3)];
    }
#pragma unroll
    for (int m = 0; m < 4; ++m)
#pragma unroll
      for (int n = 0; n < 4; ++n)
        acc[m][n] = __builtin_amdgcn_mfma_f32_16x16x32_bf16(af[m], bfv[n], acc[m][n], 0, 0, 0);
  }
}

// Fused Q/K/V projection GEMM: A = XO (n-tiles 0-3) or XS (4-11); W = WQKV [1536][512].
// 128x128 tile, 256 threads, single-buffered, 4 blocks/CU. XCD-chunked swizzle.
// Epilogue: bias, col sq-norm atomics (Q,K only), bf16 stash, coalesced store.
__global__ __launch_bounds__(256, 4) void k_qkv(
    const unsigned short* __restrict__ XO, const unsigned short* __restrict__ XS,
    const unsigned short* __restrict__ WQKV,
    const float* __restrict__ bq, const float* __restrict__ bk, const float* __restrict__ bv,
    unsigned short* __restrict__ Qb, unsigned short* __restrict__ KVb,
    float* __restrict__ sqQ, float* __restrict__ sqK) {
  __shared__ __align__(16) char smem[33792];
  unsigned short* As = (unsigned short*)smem;
  unsigned short* Bs = (unsigned short*)(smem + 16384);
  const int lin = blockIdx.x + 12 * blockIdx.y;
  const int xcd = lin & 7, j = lin >> 3;
  const int mt = xcd * 32 + j / 12;
  const int nt = j % 12;
  const int m0 = mt * 128, n0 = nt * 128;
  const unsigned short* A = (nt < 4) ? XO : XS;
  const float* bb = (nt < 4) ? (bq + n0) : (nt < 8 ? (bk + (nt - 4) * 128) : (bv + (nt - 8) * 128));
  float* sq = (nt < 4) ? sqQ : (nt < 8 ? sqK : nullptr);
  const int scol0 = (nt < 4) ? n0 : (nt - 4) * 128;
  unsigned short* ob = (nt < 4) ? Qb : KVb;
  const int ldo = (nt < 4) ? 512 : 1024;
  const int oc0 = (nt < 4) ? n0 : (nt - 4) * 128;
  const int t = threadIdx.x, w = t >> 6, lane = t & 63;
  const int wr = w >> 1, wc = w & 1, l15 = lane & 15, l4 = lane >> 4;
  f32x4 acc[4][4] = {};

  for (int kt = 0; kt < 512; kt += 64) {
    stage128(A, 512, m0, kt, (char*)As, t);
    stage128(WQKV, 512, n0, kt, (char*)Bs, t);
    __syncthreads();
    gemm_compute(As, Bs, wr, wc, l15, l4, acc);
    __syncthreads();
  }

  unsigned short* Cs = (unsigned short*)smem;  // [128][132] stash
#pragma unroll
  for (int n = 0; n < 4; ++n) {
    int cn = wc * 64 + n * 16 + l15;
    float bn = bb[cn];
    float s2 = 0.f;
#pragma unroll
    for (int m = 0; m < 4; ++m) {
      int rb = wr * 64 + m * 16 + l4 * 4;
#pragma unroll
      for (int q = 0; q < 4; ++q) {
        float v = acc[m][n][q] + bn;
        s2 += v * v;
        Cs[(rb + q) * 132 + cn] = f2b(v);
      }
    }
    if (sq) {
      s2 += __shfl_xor(s2, 16, 64);
      s2 += __shfl_xor(s2, 32, 64);
      if (l4 == 0) atomicAdd(&sq[(m0 >> 12) * Cn + scol0 + cn], s2);
    }
  }
  __syncthreads();
#pragma unroll
  for (int pass = 0; pass < 4; ++pass) {
    int r = pass * 32 + (t >> 3);
    int c = (t & 7) * 8;
    u16x8 v0 = *(const u16x8*)&Cs[r * 132 + c];
    u16x8 v1 = *(const u16x8*)&Cs[r * 132 + 64 + c];
    size_t base = (size_t)(m0 + r) * ldo + oc0;
    *(u16x8*)&ob[base + c] = v0;
    *(u16x8*)&ob[base + 64 + c] = v1;
  }
}

// FFN GEMMs. MODE 1: gelu(acc+bias). MODE 2: acc+bias+res.
// 128x128 tile, 256 threads, single-buffered, 4 blocks/CU. XCD-chunked swizzle.
template <int MODE>
__global__ __launch_bounds__(256, 4) void k_ffn(
    const unsigned short* __restrict__ A, const unsigned short* __restrict__ W,
    const float* __restrict__ bias, const unsigned short* __restrict__ res,
    unsigned short* __restrict__ out, int K, int N) {
  __shared__ __align__(16) char smem[33792];
  unsigned short* As = (unsigned short*)smem;
  unsigned short* Bs = (unsigned short*)(smem + 16384);
  const int NT = gridDim.x;
  const int lin = blockIdx.x + NT * blockIdx.y;
  const int xcd = lin & 7, j = lin >> 3;
  const int mt = xcd * 32 + j / NT;
  const int nt = j % NT;
  const int m0 = mt * 128, n0 = nt * 128;
  const int t = threadIdx.x, w = t >> 6, lane = t & 63;
  const int wr = w >> 1, wc = w & 1, l15 = lane & 15, l4 = lane >> 4;
  f32x4 acc[4][4] = {};

  for (int kt = 0; kt < K; kt += 64) {
    stage128(A, K, m0, kt, (char*)As, t);
    stage128(W, K, n0, kt, (char*)Bs, t);
    __syncthreads();
    gemm_compute(As, Bs, wr, wc, l15, l4, acc);
    __syncthreads();
  }

  unsigned short* Cs = (unsigned short*)smem;  // [128][132] stash
#pragma unroll
  for (int n = 0; n < 4; ++n) {
    int cn = wc * 64 + n * 16 + l15;
    float bn = bias[n0 + cn];
#pragma unroll
    for (int m = 0; m < 4; ++m) {
      int rb = wr * 64 + m * 16 + l4 * 4;
#pragma unroll
      for (int q = 0; q < 4; ++q) {
        float v = acc[m][n][q] + bn;
        if (MODE == 1) v = gelu_fast(v);
        Cs[(rb + q) * 132 + cn] = f2b(v);
      }
    }
  }
  __syncthreads();
#pragma unroll
  for (int pass = 0; pass < 4; ++pass) {
    int r = pass * 32 + (t >> 3);
    int c = (t & 7) * 8;
    u16x8 v0 = *(const u16x8*)&Cs[r * 132 + c];
    u16x8 v1 = *(const u16x8*)&Cs[r * 132 + 64 + c];
    size_t base = (size_t)(m0 + r) * N + n0;
    if (MODE == 2) {
      u16x8 r0 = *(const u16x8*)&res[base + c];
      u16x8 r1 = *(const u16x8*)&res[base + 64 + c];
#pragma unroll
      for (int jj = 0; jj < 8; ++jj) {
        v0[jj] = f2b(b2f(v0[jj]) + b2f(r0[jj]));
        v1[jj] = f2b(b2f(v1[jj]) + b2f(r1[jj]));
      }
    }
    *(u16x8*)&out[base + c] = v0;
    *(u16x8*)&out[base + 64 + c] = v1;
  }
}

// one K=64 compute step for the 256x256 tile: 8 waves (2M x 4N), per-wave 128x64 out.
DEVI void compute256(const unsigned short* Ab, const unsigned short* Bb,
                     int wr, int wc, int l15, int l4, f32x4 (&acc)[8][4]) {
#pragma unroll
  for (int ks = 0; ks < 2; ++ks) {
    short8 aF[8], bF[4];
#pragma unroll
    for (int mf = 0; mf < 8; ++mf) {
      int row = wr * 128 + mf * 16 + l15;
      aF[mf] = *(const short8*)&Ab[row * 64 + (((ks * 4 + l4) ^ (row & 7)) << 3)];
    }
#pragma unroll
    for (int nf = 0; nf < 4; ++nf) {
      int row = wc * 64 + nf * 16 + l15;
      bF[nf] = *(const short8*)&Bb[row * 64 + (((ks * 4 + l4) ^ (row & 7)) << 3)];
    }
#pragma unroll
    for (int mf = 0; mf < 8; ++mf)
#pragma unroll
      for (int nf = 0; nf < 4; ++nf)
        acc[mf][nf] = __builtin_amdgcn_mfma_f32_16x16x32_bf16(aF[mf], bF[nf], acc[mf][nf], 0, 0, 0);
  }
}

// Final: out[b,c,n] = wo@U + bo + xo. 256x256 tile, 2-phase dbuf.
// Residual xo comes from the bf16 LN output XO [pix][C] via an LDS transpose
// (c-major u16 [64][258]); saves the 134 MB fp32 x_opt re-read + LN recompute.
__global__ __launch_bounds__(512, 2) void k_gemm_out(
    const unsigned short* __restrict__ Wo, const unsigned short* __restrict__ U,
    const float* __restrict__ bo, const unsigned short* __restrict__ XO,
    float* __restrict__ out) {
  __shared__ __align__(16) char smem[131072];
  const int lin = blockIdx.x;
  const int xcd = lin & 7, j = lin >> 3;
  const int b = xcd, mt = j & 1, nt = j >> 1;
  const int m0 = mt * 256, n0 = nt * 256;
  const unsigned short* Ub = U + (size_t)b * HWn * Cn;
  const int t = threadIdx.x, lane = t & 63;
  const int w = t >> 6, wr = w >> 2, wc = w & 3;
  const int l15 = lane & 15, l4 = lane >> 4;
  f32x4 acc[8][4] = {};

  stage256(Wo, 512, m0, 0, smem, t);
  stage256(Ub, 512, n0, 0, smem + 32768, t);
  __syncthreads();
  for (int kt = 0; kt < 8; ++kt) {
    if (kt + 1 < 8) {
      char* nb = smem + ((kt + 1) & 1) * 65536;
      stage256(Wo, 512, m0, (kt + 1) * 64, nb, t);
      stage256(Ub, 512, n0, (kt + 1) * 64, nb + 32768, t);
    }
    const unsigned short* Ab = (const unsigned short*)(smem + (kt & 1) * 65536);
    const unsigned short* Bb = (const unsigned short*)(smem + (kt & 1) * 65536 + 32768);
    compute256(Ab, Bb, wr, wc, l15, l4, acc);
    __syncthreads();
  }

  float* Fs = (float*)smem;                               // [64][260] f32 acc stash
  unsigned short* XOs = (unsigned short*)(smem + 66560);  // [64][258] bf16, c-major
#pragma unroll
  for (int qd = 0; qd < 4; ++qd) {
    __syncthreads();
    if (wr == (qd >> 1)) {
#pragma unroll
      for (int nf = 0; nf < 4; ++nf) {
        int cn = wc * 64 + nf * 16 + l15;
#pragma unroll
        for (int mf2 = 0; mf2 < 4; ++mf2) {
          int mf = (qd & 1) * 4 + mf2;
#pragma unroll
          for (int q = 0; q < 4; ++q)
            Fs[(mf2 * 16 + l4 * 4 + q) * 260 + cn] = acc[mf][nf][q];
        }
      }
    }
    // stage XO tile (256 pix x 64 c) transposed into XOs[c][pix]
#pragma unroll
    for (int i = 0; i < 4; ++i) {
      int idx = i * 512 + t;
      int r = idx >> 3, c8 = idx & 7;
      u16x8 v = *(const u16x8*)&XO[(size_t)(b * HWn + n0 + r) * Cn + m0 + qd * 64 + c8 * 8];
#pragma unroll
      for (int jx = 0; jx < 8; ++jx) XOs[(c8 * 8 + jx) * 258 + r] = v[jx];
    }
    __syncthreads();
#pragma unroll
    for (int p = 0; p < 8; ++p) {
      int cl = p * 8 + w;            // wave-uniform channel row within quarter
      int px = lane * 4;             // 4 contiguous pixels per lane -> 1KB/wave
      int c = m0 + qd * 64 + cl;
      size_t gbase = (size_t)(b * Cn + c) * HWn + n0 + px;
      f32x4 z = *(const f32x4*)&Fs[cl * 260 + px];
      u16x2 x01 = *(const u16x2*)&XOs[cl * 258 + px];
      u16x2 x23 = *(const u16x2*)&XOs[cl * 258 + px + 2];
      float bc = bo[c];
      f32x4 o;
      o[0] = z[0] + bc + b2f(x01[0]);
      o[1] = z[1] + bc + b2f(x01[1]);
      o[2] = z[2] + bc + b2f(x23[0]);
      o[3] = z[3] + bc + b2f(x23[1]);
      *(f32x4*)&out[gbase] = o;
    }
  }
}

// Z = V_head @ P  (M=128 pixels, N=64, K=64), epilogue adds z_opt (= XO, same layout)
__global__ __launch_bounds__(256, 2) void k_z(
    const unsigned short* __restrict__ V, int ldv, const unsigned short* __restrict__ PT,
    const unsigned short* __restrict__ XO, unsigned short* __restrict__ ZS) {
  __shared__ __align__(16) char smem[24576];
  unsigned short* As = (unsigned short*)smem;
  unsigned short* Bs = (unsigned short*)(smem + 16384);
  const int mt = blockIdx.x, bh = blockIdx.y, b = bh >> 3, h = bh & 7;
  const int t = threadIdx.x, w = t >> 6, lane = t & 63;
  const int wr = w >> 1, wc = w & 1, l15 = lane & 15, l4 = lane >> 4;
  const int srow = t >> 3, sph = t & 7;
#pragma unroll
  for (int i = 0; i < 4; ++i) {
    int row = i * 32 + srow;
    int slog = sph ^ (row & 7);
    async16(V + (size_t)(b * HWn + mt * 128 + row) * ldv + h * 64 + slog * 8,
            (char*)As + i * 4096 + w * 1024);
  }
#pragma unroll
  for (int i = 0; i < 2; ++i) {
    int row = i * 32 + srow;
    int slog = sph ^ (row & 7);
    async16(PT + (size_t)bh * 4096 + row * 64 + slog * 8, (char*)Bs + i * 4096 + w * 1024);
  }
  __syncthreads();
  f32x4 acc[4][2] = {};
#pragma unroll
  for (int ks = 0; ks < 2; ++ks) {
    short8 af[4], bfv[2];
#pragma unroll
    for (int m = 0; m < 4; ++m) {
      int row = wr * 64 + m * 16 + l15;
      int slog = ks * 4 + l4;
      af[m] = *(const short8*)&As[row * 64 + ((slog ^ (row & 7)) << 3)];
    }
#pragma unroll
    for (int n = 0; n < 2; ++n) {
      int row = wc * 32 + n * 16 + l15;
      int slog = ks * 4 + l4;
      bfv[n] = *(const short8*)&Bs[row * 64 + ((slog ^ (row & 7)) << 3)];
    }
#pragma unroll
    for (int m = 0; m < 4; ++m)
#pragma unroll
      for (int n = 0; n < 2; ++n)
        acc[m][n] = __builtin_amdgcn_mfma_f32_16x16x32_bf16(af[m], bfv[n], acc[m][n], 0, 0, 0);
  }
  __syncthreads();
  unsigned short* Cs = (unsigned short*)smem;  // [128][72]
#pragma unroll
  for (int n = 0; n < 2; ++n) {
    int e = wc * 32 + n * 16 + l15;
#pragma unroll
    for (int m = 0; m < 4; ++m) {
      int rb = wr * 64 + m * 16 + l4 * 4;
#pragma unroll
      for (int q = 0; q < 4; ++q) Cs[(rb + q) * 72 + e] = f2b(acc[m][n][q]);
    }
  }
  __syncthreads();
#pragma unroll
  for (int pass = 0; pass < 4; ++pass) {
    int r = pass * 32 + (t >> 3);
    int c = (t & 7) * 8;
    u16x8 v = *(const u16x8*)&Cs[r * 72 + c];
    size_t idx = (size_t)(b * HWn + mt * 128 + r) * Cn + h * 64 + c;
    u16x8 xo = *(const u16x8*)&XO[idx];
#pragma unroll
    for (int jj = 0; jj < 8; ++jj) v[jj] = f2b(b2f(v[jj]) + b2f(xo[jj]));
    *(u16x8*)&ZS[idx] = v;
  }
}

// LayerNorm over C per pixel; writes transposed bf16 [pixel, C]. z=0: x_opt; z=1: x_sar.
__global__ __launch_bounds__(256, 2) void k_ln(
    const float* __restrict__ x_opt, const float* __restrict__ x_sar,
    const float* __restrict__ lwo, const float* __restrict__ lbo,
    const float* __restrict__ lws, const float* __restrict__ lbs,
    unsigned short* __restrict__ XO, unsigned short* __restrict__ XS) {
  const int zz = blockIdx.z;
  const float* x = zz ? x_sar : x_opt;
  const float* lw = zz ? lws : lwo;
  const float* lb = zz ? lbs : lbo;
  unsigned short* out = zz ? XS : XO;
  __shared__ unsigned short stash[512 * 34];
  __shared__ float redS[256 * 4], redQ[256 * 4];
  __shared__ float meanS[32], rstdS[32], wS[512], bS[512];
  const int b = blockIdx.y, n0 = blockIdx.x * 32;
  const int t = threadIdx.x;
  wS[t] = lw[t]; wS[t + 256] = lw[t + 256];
  bS[t] = lb[t]; bS[t + 256] = lb[t + 256];
  const int cg = t >> 3, pq = t & 7;
  float sum[4] = {}, sq[4] = {};
  for (int r = 0; r < 16; ++r) {
    int c = r * 32 + cg;
    f32x4 v = *(const f32x4*)(x + (size_t)(b * Cn + c) * HWn + n0 + pq * 4);
#pragma unroll
    for (int j = 0; j < 4; ++j) { sum[j] += v[j]; sq[j] += v[j] * v[j]; }
    u16x2 h0 = {f2b(v[0]), f2b(v[1])};
    u16x2 h1 = {f2b(v[2]), f2b(v[3])};
    *(u16x2*)&stash[c * 34 + pq * 4] = h0;
    *(u16x2*)&stash[c * 34 + pq * 4 + 2] = h1;
  }
#pragma unroll
  for (int j = 0; j < 4; ++j) { redS[t * 4 + j] = sum[j]; redQ[t * 4 + j] = sq[j]; }
  __syncthreads();
  if (t < 32) {
    float s = 0.f, qq = 0.f;
    int pqq = t >> 2, j = t & 3;
    for (int g = 0; g < 32; ++g) {
      s += redS[(g * 8 + pqq) * 4 + j];
      qq += redQ[(g * 8 + pqq) * 4 + j];
    }
    float mean = s * (1.0f / 512.0f);
    float var = qq * (1.0f / 512.0f) - mean * mean;
    float rstd = rsqrtf(var + 1e-5f);
    meanS[t] = mean; rstdS[t] = rstd;
  }
  __syncthreads();
  const int p = t >> 3, cs = t & 7;
  float mn = meanS[p], rs = rstdS[p];
  for (int ch = 0; ch < 4; ++ch) {
    u16x8 o0, o1;
#pragma unroll
    for (int j = 0; j < 16; ++j) {
      int c = ch * 128 + cs * 16 + j;
      float xv = b2f(stash[c * 34 + p]);
      unsigned short r2 = f2b((xv - mn) * rs * wS[c] + bS[c]);
      if (j < 8) o0[j] = r2; else o1[j - 8] = r2;
    }
    size_t base = (size_t)(b * HWn + n0 + p) * Cn + ch * 128 + cs * 16;
    *(u16x8*)&out[base] = o0;
    *(u16x8*)&out[base + 8] = o1;
  }
}

// MFMA partial Gram over a 512-row slice: Praw[bh][d][e] += sum_n Q[n,d]*K[n,e].
__global__ __launch_bounds__(256, 2) void k_attn_part(
    const unsigned short* __restrict__ Q, int ldq,
    const unsigned short* __restrict__ Kb, int ldk,
    float* __restrict__ Praw) {
  __shared__ __align__(16) unsigned short QT[64 * 136];
  __shared__ __align__(16) unsigned short KT[64 * 136];
  const int bh = blockIdx.x, ns = blockIdx.y, b = bh >> 3, h = bh & 7;
  const int t = threadIdx.x, w = t >> 6, lane = t & 63;
  const int l15 = lane & 15, l4 = lane >> 4;
  const int dh = w >> 1, eh = w & 1;
  const int c8 = t >> 5, rr = t & 31;
  f32x4 acc[2][2] = {};
  for (int chunk = 0; chunk < 4; ++chunk) {
    int n0 = ns * 512 + chunk * 128;
    __syncthreads();
#pragma unroll
    for (int pass = 0; pass < 2; ++pass) {
      int row = n0 + pass * 64 + 2 * rr;
      u16x8 q0 = *(const u16x8*)(Q + (size_t)(b * HWn + row) * ldq + h * 64 + c8 * 8);
      u16x8 q1 = *(const u16x8*)(Q + (size_t)(b * HWn + row + 1) * ldq + h * 64 + c8 * 8);
      u16x8 k0 = *(const u16x8*)(Kb + (size_t)(b * HWn + row) * ldk + h * 64 + c8 * 8);
      u16x8 k1 = *(const u16x8*)(Kb + (size_t)(b * HWn + row + 1) * ldk + h * 64 + c8 * 8);
#pragma unroll
      for (int j = 0; j < 8; ++j) {
        u16x2 pq = {q0[j], q1[j]};
        u16x2 pk = {k0[j], k1[j]};
        *(u16x2*)&QT[(c8 * 8 + j) * 136 + pass * 64 + 2 * rr] = pq;
        *(u16x2*)&KT[(c8 * 8 + j) * 136 + pass * 64 + 2 * rr] = pk;
      }
    }
    __syncthreads();
#pragma unroll
    for (int ks = 0; ks < 4; ++ks) {
      short8 af[2], bfv[2];
#pragma unroll
      for (int m = 0; m < 2; ++m)
        af[m] = *(const short8*)&QT[(dh * 32 + m * 16 + l15) * 136 + ks * 32 + l4 * 8];
#pragma unroll
      for (int n = 0; n < 2; ++n)
        bfv[n] = *(const short8*)&KT[(eh * 32 + n * 16 + l15) * 136 + ks * 32 + l4 * 8];
#pragma unroll
      for (int m = 0; m < 2; ++m)
#pragma unroll
        for (int n = 0; n < 2; ++n)
          acc[m][n] = __builtin_amdgcn_mfma_f32_16x16x32_bf16(af[m], bfv[n], acc[m][n], 0, 0, 0);
    }
  }
#pragma unroll
  for (int m = 0; m < 2; ++m)
#pragma unroll
    for (int n = 0; n < 2; ++n)
#pragma unroll
      for (int q = 0; q < 4; ++q) {
        int dd = dh * 32 + m * 16 + l4 * 4 + q;
        int ee = eh * 32 + n * 16 + l15;
        atomicAdd(&Praw[(size_t)bh * 4096 + dd * 64 + ee], acc[m][n][q]);
      }
}

// scale by rq*rk/8, row softmax, store PT[bh][e][d] bf16 (layout k_z consumes)
__global__ __launch_bounds__(256, 2) void k_softmax(
    const float* __restrict__ Praw, const float* __restrict__ sqQ,
    const float* __restrict__ sqK, unsigned short* __restrict__ PT) {
  __shared__ float P3[64 * 66];
  const int bh = blockIdx.x, b = bh >> 3, h = bh & 7;
  const int t = threadIdx.x, w = t >> 6, lane = t & 63;
  float rk = 1.0f / fmaxf(sqrtf(sqK[b * Cn + h * 64 + lane]), 1e-12f);
  for (int i = 0; i < 16; ++i) {
    int d = w * 16 + i;
    float rqd = 1.0f / fmaxf(sqrtf(sqQ[b * Cn + h * 64 + d]), 1e-12f);
    float v = Praw[(size_t)bh * 4096 + d * 64 + lane] * (rqd * rk * 0.125f);
    float m = v;
    for (int o = 32; o > 0; o >>= 1) m = fmaxf(m, __shfl_xor(m, o, 64));
    float p = __expf(v - m);
    float s = p;
    for (int o = 32; o > 0; o >>= 1) s += __shfl_xor(s, o, 64);
    P3[lane * 66 + d] = p / s;  // transposed: [e][d]
  }
  __syncthreads();
  {
    int e = t >> 2, dg = (t & 3) * 16;
    u16x8 o0, o1;
#pragma unroll
    for (int j = 0; j < 8; ++j) {
      o0[j] = f2b(P3[e * 66 + dg + j]);
      o1[j] = f2b(P3[e * 66 + dg + 8 + j]);
    }
    size_t base = (size_t)bh * 4096 + e * 64 + dg;
    *(u16x8*)&PT[base] = o0;
    *(u16x8*)&PT[base + 8] = o1;
  }
}

// weight prep: bf16 converts (packed WQKV + WO) and transposed W1T/W2T in one kernel
__global__ void k_prep(const float* __restrict__ wq, const float* __restrict__ wk,
                       const float* __restrict__ wv, const float* __restrict__ wo,
                       const float* __restrict__ w1, const float* __restrict__ w2,
                       unsigned short* __restrict__ WQKV, unsigned short* __restrict__ WO,
                       unsigned short* __restrict__ W1T, unsigned short* __restrict__ W2T) {
  int bid = blockIdx.x;
  if (bid < 1024) {
    const int mat = bid >> 8, chunk = bid & 255;
    const float* s = mat == 0 ? wq : mat == 1 ? wk : mat == 2 ? wv : wo;
    unsigned short* d = mat == 3 ? WO : (WQKV + mat * 262144);
    int idx = chunk * 1024 + threadIdx.x * 4;
    f32x4 v = *(const f32x4*)(s + idx);
    u16x4 o = {f2b(v[0]), f2b(v[1]), f2b(v[2]), f2b(v[3])};
    *(u16x4*)(d + idx) = o;
    return;
  }
  bid -= 1024;
  __shared__ float tile[32][33];
  const float* src; unsigned short* dst; int R, C, r0, c0;
  if (bid < 512) { src = w1; dst = W1T; R = 512; C = 1024; r0 = (bid >> 5) * 32; c0 = (bid & 31) * 32; }
  else { bid -= 512; src = w2; dst = W2T; R = 1024; C = 512; r0 = (bid >> 4) * 32; c0 = (bid & 15) * 32; }
  const int tx = threadIdx.x & 31, ty = threadIdx.x >> 5;
#pragma unroll
  for (int i = 0; i < 4; ++i)
    tile[ty + i * 8][tx] = src[(size_t)(r0 + ty + i * 8) * C + c0 + tx];
  __syncthreads();
#pragma unroll
  for (int i = 0; i < 4; ++i)
    dst[(size_t)(c0 + ty + i * 8) * R + r0 + tx] = f2b(tile[tx][ty + i * 8]);
}

extern "C" void kernel_launch(void* const* d_in, const int* in_sizes, int n_in,
                              void* d_out, int out_size, void* d_ws, size_t ws_size,
                              hipStream_t stream) {
  const float* x_opt = (const float*)d_in[0];
  const float* x_sar = (const float*)d_in[1];
  const float* ln_o_w = (const float*)d_in[2];
  const float* ln_o_b = (const float*)d_in[3];
  const float* ln_s_w = (const float*)d_in[4];
  const float* ln_s_b = (const float*)d_in[5];
  const float* wq = (const float*)d_in[6];
  const float* bq = (const float*)d_in[7];
  const float* wk = (const float*)d_in[8];
  const float* bk = (const float*)d_in[9];
  const float* wv = (const float*)d_in[10];
  const float* bv = (const float*)d_in[11];
  const float* w1 = (const float*)d_in[12];
  const float* b1 = (const float*)d_in[13];
  const float* w2 = (const float*)d_in[14];
  const float* b2 = (const float*)d_in[15];
  const float* wo = (const float*)d_in[16];
  const float* bo = (const float*)d_in[17];
  float* out = (float*)d_out;

  char* ws = (char*)d_ws;
  const size_t S = (size_t)Mtot * Cn * 2;  // 33,554,432
  unsigned short* XO = (unsigned short*)(ws);
  unsigned short* XS = (unsigned short*)(ws + S);
  unsigned short* Qb = (unsigned short*)(ws + 2 * S);
  unsigned short* KVb = (unsigned short*)(ws + 3 * S);  // [32768][1024]: K cols 0-511, V 512-1023
  unsigned short* ZS = (unsigned short*)(ws + 5 * S);
  unsigned short* H1 = Qb;  // alias: [2S,4S) — Q and K/V dead after attention
  unsigned short* Ub = XS;  // alias: XS dead after KV GEMM
  char* E = ws + 6 * S;
  unsigned short* PT = (unsigned short*)(E);                       // 524288
  float* Praw = (float*)(E + 524288);                              // 1048576
  float* sqQ = (float*)(E + 524288 + 1048576);                     // 16384
  float* sqK = (float*)(E + 524288 + 1048576 + 16384);             // 16384
  char* Wb = E + 1867776;
  unsigned short* WQKV = (unsigned short*)(Wb);          // [1536][512] packed Q,K,V
  unsigned short* WO = (unsigned short*)(Wb + 1572864);
  unsigned short* W1T = (unsigned short*)(Wb + 2097152);
  unsigned short* W2T = (unsigned short*)(Wb + 2097152 + 1048576);

  // zero the atomic targets (Praw, sqQ, sqK are contiguous)
  hipMemsetAsync(E + 524288, 0, 1048576 + 32768, stream);

  k_prep<<<2048, 256, 0, stream>>>(wq, wk, wv, wo, w1, w2, WQKV, WO, W1T, W2T);

  k_ln<<<dim3(128, Bn, 2), 256, 0, stream>>>(x_opt, x_sar, ln_o_w, ln_o_b, ln_s_w, ln_s_b,
                                             XO, XS);

  k_qkv<<<dim3(12, 256), 256, 0, stream>>>(XO, XS, WQKV, bq, bk, bv, Qb, KVb, sqQ, sqK);

  k_attn_part<<<dim3(64, 8), 256, 0, stream>>>(Qb, 512, KVb, 1024, Praw);
  k_softmax<<<64, 256, 0, stream>>>(Praw, sqQ, sqK, PT);
  k_z<<<dim3(32, 64), 256, 0, stream>>>(KVb + 512, 1024, PT, XO, ZS);

  k_ffn<1><<<dim3(8, 256), 256, 0, stream>>>(ZS, W1T, b1, nullptr, H1, 512, 1024);
  k_ffn<2><<<dim3(4, 256), 256, 0, stream>>>(H1, W2T, b2, ZS, Ub, 1024, 512);
  k_gemm_out<<<256, 512, 0, stream>>>(WO, Ub, bo, XO, out);
}